// Round 8
// baseline (394.716 us; speedup 1.0000x reference)
//
#include <hip/hip_runtime.h>

#define N_PIX 16384
#define CC 192
#define C3 576
#define KTOT 192
#define NCH 32
#define CHUNK 512

typedef __bf16 bf16_t;
typedef bf16_t bf16x4 __attribute__((ext_vector_type(4)));
typedef bf16_t bf16x8 __attribute__((ext_vector_type(8)));
typedef float f32x4 __attribute__((ext_vector_type(4)));

struct WPtrs { const float* p[4]; };
struct GArgs { const float* W[16]; long xoff[16]; };

// ---------------- MFMA GEMM: Y[m][n] = sum_k W[m][k] * X[k][n], K=192 --------
// 64m x 256n tile. W staged to LDS once for all K. X double-buffered register
// prefetch: tile t+1's 32 strided loads issue BEFORE the barrier, so their
// latency hides under sync + ds_read + MFMA + sync of tile t (T14 deep split).
// A/B frags share k-bijection phi(gi,e)=16*(e>>2)+4*gi+(e&3); C/D map
// col=lane&15, row=4*(lane>>4)+reg [m89-verified].
template <typename XT, typename YT>
__global__ __launch_bounds__(256) void gemm_k192(GArgs ga,
    const XT* __restrict__ X, YT* __restrict__ Y, long sY)
{
    __shared__ __align__(16) bf16_t Wl[64][200];   // 64m x 192k (+8 pad)
    __shared__ __align__(16) bf16_t Xl[256][36];   // 256n x 32k (+4 pad)
    const int bt = blockIdx.z;
    const float* __restrict__ W = ga.W[bt];
    const XT* __restrict__ Xb = X + ga.xoff[bt];
    YT* __restrict__ Yb = Y + (long)bt * sY;
    const int m0 = blockIdx.y * 64, n0 = blockIdx.x * 256;
    const int tid = threadIdx.x;
    const int w = tid >> 6;
    const int gi = (tid >> 4) & 3;
    const int li = tid & 15;

    // stage all of W: 4 threads/row, each 48 k = 6 bf16x8 segments
    {
        const int wr = tid >> 2, wkb = (tid & 3) * 48;
        #pragma unroll
        for (int j = 0; j < 6; ++j) {
            const float* wp0 = W + (long)(m0 + wr) * KTOT + wkb + 8 * j;
            float4 a = *(const float4*)(wp0);
            float4 b = *(const float4*)(wp0 + 4);
            bf16x8 v = { (bf16_t)a.x, (bf16_t)a.y, (bf16_t)a.z, (bf16_t)a.w,
                         (bf16_t)b.x, (bf16_t)b.y, (bf16_t)b.z, (bf16_t)b.w };
            *(bf16x8*)&Wl[wr][wkb + 8 * j] = v;
        }
    }

    f32x4 acc[4][4];
    #pragma unroll
    for (int i = 0; i < 4; ++i)
        #pragma unroll
        for (int j = 0; j < 4; ++j) acc[i][j] = 0.f;

    XT xa[32], xb[32];
    {   // prologue: tile 0 -> xa
        const XT* xp = Xb + n0 + tid;
        #pragma unroll
        for (int g = 0; g < 32; ++g) xa[g] = xp[(long)g * N_PIX];
    }

    #pragma unroll
    for (int t = 0; t < 6; ++t) {
        XT* cur = (t & 1) ? xb : xa;        // static after unroll (rule #20)
        XT* nxt = (t & 1) ? xa : xb;
        // write prefetched regs -> LDS (column tid); waits vmcnt for cur
        #pragma unroll
        for (int g = 0; g < 8; ++g) {
            bf16x4 v = { (bf16_t)cur[4 * g + 0], (bf16_t)cur[4 * g + 1],
                         (bf16_t)cur[4 * g + 2], (bf16_t)cur[4 * g + 3] };
            *(bf16x4*)&Xl[tid][g * 4] = v;
        }
        // issue next tile's loads BEFORE the barrier
        if (t < 5) {
            const XT* xp = Xb + (long)((t + 1) * 32) * N_PIX + n0 + tid;
            #pragma unroll
            for (int g = 0; g < 32; ++g) nxt[g] = xp[(long)g * N_PIX];
        }
        __syncthreads();
        bf16x8 af[4], bfr[4];
        #pragma unroll
        for (int mi = 0; mi < 4; ++mi) {
            bf16x4 lo = *(const bf16x4*)&Wl[16 * mi + li][32 * t + 4 * gi];
            bf16x4 hi = *(const bf16x4*)&Wl[16 * mi + li][32 * t + 16 + 4 * gi];
            af[mi] = __builtin_shufflevector(lo, hi, 0, 1, 2, 3, 4, 5, 6, 7);
        }
        #pragma unroll
        for (int ni = 0; ni < 4; ++ni) {
            const int n = 64 * w + 16 * ni + li;
            bf16x4 lo = *(const bf16x4*)&Xl[n][4 * gi];
            bf16x4 hi = *(const bf16x4*)&Xl[n][16 + 4 * gi];
            bfr[ni] = __builtin_shufflevector(lo, hi, 0, 1, 2, 3, 4, 5, 6, 7);
        }
        #pragma unroll
        for (int mi = 0; mi < 4; ++mi)
            #pragma unroll
            for (int ni = 0; ni < 4; ++ni)
                acc[mi][ni] = __builtin_amdgcn_mfma_f32_16x16x32_bf16(
                    af[mi], bfr[ni], acc[mi][ni], 0, 0, 0);
        __syncthreads();
    }
    #pragma unroll
    for (int mi = 0; mi < 4; ++mi)
        #pragma unroll
        for (int ni = 0; ni < 4; ++ni) {
            const int n = n0 + 64 * w + 16 * ni + li;
            #pragma unroll
            for (int r = 0; r < 4; ++r) {
                const int m = m0 + 16 * mi + 4 * gi + r;
                Yb[(long)m * N_PIX + n] = (YT)acc[mi][ni][r];
            }
        }
}

// ---------------- depthwise 3x3 + fused row L2-norm ----------------
// One block = one (channel, image) = one full norm row. For ch<384 (q,k),
// block-reduce sum(z^2) over the 128x128 output and write invn directly.
__global__ __launch_bounds__(256) void dwconv3b(const bf16_t* __restrict__ Yin,
    const float* __restrict__ wdw, bf16_t* __restrict__ Z,
    float* __restrict__ invn)
{
    const int ch = blockIdx.x, sb = blockIdx.y;
    const int tid = threadIdx.x;
    const int x0 = (tid & 15) << 3;          // 16 col-groups x 8
    const int y0 = (tid >> 4) << 3;          // 16 row-strips x 8
    const bf16_t* __restrict__ inp = Yin + (long)(sb * C3 + ch) * N_PIX;
    bf16_t* __restrict__ outp = Z + (long)(sb * C3 + ch) * N_PIX;
    const float* wch = wdw + ch * 9;
    const float w00 = wch[0], w01 = wch[1], w02 = wch[2];
    const float w10 = wch[3], w11 = wch[4], w12 = wch[5];
    const float w20 = wch[6], w21 = wch[7], w22 = wch[8];
    const bool hasL = (x0 > 0), hasR = (x0 < 120);
    float A[10], B[10], Cr[10];   // [0]=x0-1, [1..8]=x0..x0+7, [9]=x0+8
    auto loadrow = [&](int yy, float* r) {
        if (yy < 0 || yy > 127) {
            #pragma unroll
            for (int i = 0; i < 10; ++i) r[i] = 0.f;
            return;
        }
        const bf16_t* p = inp + (yy << 7);
        bf16x8 v = *(const bf16x8*)(p + x0);
        #pragma unroll
        for (int j = 0; j < 8; ++j) r[1 + j] = (float)v[j];
        r[0] = hasL ? (float)p[x0 - 1] : 0.f;
        r[9] = hasR ? (float)p[x0 + 8] : 0.f;
    };
    loadrow(y0 - 1, A);
    loadrow(y0,     B);
    float ss = 0.f;
    #pragma unroll
    for (int r = 0; r < 8; ++r) {
        loadrow(y0 + r + 1, Cr);
        bf16x8 ov;
        #pragma unroll
        for (int i = 0; i < 8; ++i) {
            float s;
            s = fmaf(w00, A[i],  fmaf(w01, A[i + 1],  w02 * A[i + 2]));
            s = fmaf(w10, B[i],  fmaf(w11, B[i + 1],  fmaf(w12, B[i + 2], s)));
            s = fmaf(w20, Cr[i], fmaf(w21, Cr[i + 1], fmaf(w22, Cr[i + 2], s)));
            ov[i] = (bf16_t)s;
            const float vb = (float)ov[i];   // norm of the bf16-rounded value
            ss = fmaf(vb, vb, ss);
        }
        *(bf16x8*)(outp + ((y0 + r) << 7) + x0) = ov;
        #pragma unroll
        for (int i = 0; i < 10; ++i) { A[i] = B[i]; B[i] = Cr[i]; }
    }
    if (ch < 384) {
        #pragma unroll
        for (int off = 32; off > 0; off >>= 1) ss += __shfl_down(ss, off);
        __shared__ float red[4];
        if ((tid & 63) == 0) red[tid >> 6] = ss;
        __syncthreads();
        if (tid == 0) {
            const float t = red[0] + red[1] + red[2] + red[3];
            const int row = (sb >> 2) * 1536 + (sb & 3) * 384 + ch;
            invn[row] = 1.f / fmaxf(sqrtf(t), 1e-12f);
        }
    }
}

// ---------------- MFMA score partials: all 4 combos share one LDS stage ------
// block = (chunk, b*4+h); wave m = combo (ee, dd, ed, de).
__global__ __launch_bounds__(256) void scores_mfma(const bf16_t* __restrict__ Z,
                                                   float* __restrict__ part)
{
    const int c = blockIdx.x;
    const int bh = blockIdx.y;
    const int b = bh >> 2, h = bh & 3;
    __shared__ __align__(16) bf16_t T[4][48][72];   // qe, qd, ke, kd
    const int tid = threadIdx.x;
    const int m = tid >> 6;
    const int gi = (tid >> 4) & 3, li = tid & 15;
    const int qs = (m == 1 || m == 3) ? 1 : 0;
    const int ks = (m == 1 || m == 2) ? 1 : 0;
    f32x4 acc[3][3];
    #pragma unroll
    for (int i = 0; i < 3; ++i)
        #pragma unroll
        for (int j = 0; j < 3; ++j) acc[i][j] = 0.f;

    const int nbase = c * CHUNK;
    for (int k0 = 0; k0 < CHUNK; k0 += 64) {
        __syncthreads();
        for (int l = tid; l < 1536; l += 256) {
            const int t = l / 384;
            const int rem = l - t * 384;
            const int r = rem >> 3, s = rem & 7;
            const int sidx = (t < 2) ? t : (t - 2);
            const int qk = (t < 2) ? 0 : 1;
            const bf16_t* gp = Z + ((long)((sidx * 4 + b) * C3 + qk * 192 + h * 48 + r)) * N_PIX
                                 + nbase + k0 + s * 8;
            *(bf16x8*)&T[t][r][s * 8] = *(const bf16x8*)gp;
        }
        __syncthreads();
        #pragma unroll
        for (int k2 = 0; k2 < 64; k2 += 32) {
            bf16x8 af[3], bfr[3];
            #pragma unroll
            for (int i = 0; i < 3; ++i) {
                bf16x4 lo = *(const bf16x4*)&T[qs][16 * i + li][k2 + 4 * gi];
                bf16x4 hi = *(const bf16x4*)&T[qs][16 * i + li][k2 + 16 + 4 * gi];
                af[i] = __builtin_shufflevector(lo, hi, 0, 1, 2, 3, 4, 5, 6, 7);
            }
            #pragma unroll
            for (int j = 0; j < 3; ++j) {
                bf16x4 lo = *(const bf16x4*)&T[2 + ks][16 * j + li][k2 + 4 * gi];
                bf16x4 hi = *(const bf16x4*)&T[2 + ks][16 * j + li][k2 + 16 + 4 * gi];
                bfr[j] = __builtin_shufflevector(lo, hi, 0, 1, 2, 3, 4, 5, 6, 7);
            }
            #pragma unroll
            for (int i = 0; i < 3; ++i)
                #pragma unroll
                for (int j = 0; j < 3; ++j)
                    acc[i][j] = __builtin_amdgcn_mfma_f32_16x16x32_bf16(
                        af[i], bfr[j], acc[i][j], 0, 0, 0);
        }
    }
    const long base = ((long)(m * 16 + bh) * NCH + c) * 2304;
    #pragma unroll
    for (int i = 0; i < 3; ++i)
        #pragma unroll
        for (int j = 0; j < 3; ++j) {
            const int e = 16 * j + li;
            #pragma unroll
            for (int r = 0; r < 4; ++r) {
                const int d = 16 * i + 4 * gi + r;
                part[base + d * 48 + e] = acc[i][j][r];
            }
        }
}

// ---------------- reduce partials, scale by norms+temperature, softmax -------
__global__ __launch_bounds__(256) void reduce_softmax(const float* __restrict__ part,
    const float* __restrict__ invn, const float* __restrict__ temp,
    float* __restrict__ attn)
{
    const int mbh = blockIdx.x;                 // 64
    const int m = mbh >> 4, b = (mbh >> 2) & 3, h = mbh & 3;
    const int qs = (m == 1 || m == 3) ? 1 : 0;
    const int ks = (m == 1 || m == 2) ? 1 : 0;
    __shared__ float sm[48][48];
    const int tid = threadIdx.x;
    const long pbase = (long)mbh * NCH * 2304;
    const float T = temp[h];
    for (int idx = tid; idx < 2304; idx += 256) {
        float v = 0.f;
        #pragma unroll 8
        for (int c = 0; c < NCH; ++c) v += part[pbase + c * 2304 + idx];
        const int d = idx / 48, e = idx % 48;
        const float iq = invn[(qs * 4 + b) * 384 + h * 48 + d];
        const float ik = invn[(ks * 4 + b) * 384 + 192 + h * 48 + e];
        sm[d][e] = v * iq * ik * T;
    }
    __syncthreads();
    if (tid < 48) {
        float mx = -1e30f;
        #pragma unroll
        for (int e = 0; e < 48; ++e) mx = fmaxf(mx, sm[tid][e]);
        float sum = 0.f;
        #pragma unroll
        for (int e = 0; e < 48; ++e) {
            const float v = __expf(sm[tid][e] - mx);
            sm[tid][e] = v;
            sum += v;
        }
        const float inv = 1.f / sum;
        const long abase = (long)mbh * 2304 + (long)tid * 48;
        #pragma unroll
        for (int e = 0; e < 48; ++e) attn[abase + e] = sm[tid][e] * inv;
    }
}

// ---------------- fold attn into projection: M[m][b][o][h*48+e] --------------
// m==3 (inter_de): einsum '...de,bhen->bhdn' SUMS the ellipsis dims.
__global__ __launch_bounds__(256) void make_M(const float* __restrict__ attn,
                                              WPtrs wp, float* __restrict__ M)
{
    const int h = blockIdx.x & 3;
    const int b = (blockIdx.x >> 2) & 3;
    const int m = blockIdx.x >> 4;              // grid 64
    __shared__ float A[48][48];
    const int tid = threadIdx.x;
    if (m == 3) {
        for (int l = tid; l < 2304; l += 256) {
            float s = 0.f;
            #pragma unroll
            for (int bb = 0; bb < 16; ++bb)
                s += attn[(long)(48 + bb) * 2304 + l];
            A[l / 48][l % 48] = s;
        }
    } else {
        const long ab = (long)(m * 16 + b * 4 + h) * 2304;
        for (int l = tid; l < 2304; l += 256)
            A[l / 48][l % 48] = attn[ab + l];
    }
    __syncthreads();
    const float* W = wp.p[m];
    float* Mo = M + (long)(m * 4 + b) * 192 * 192;
    for (int o = tid >> 4; o < 192; o += 16) {
        const float* wrow = W + (long)o * 192 + h * 48;
        for (int e2 = tid & 15; e2 < 48; e2 += 16) {
            float s = 0.f;
            #pragma unroll
            for (int d = 0; d < 48; ++d) s = fmaf(wrow[d], A[d][e2], s);
            Mo[(long)o * 192 + h * 48 + e2] = s;
        }
    }
}

extern "C" void kernel_launch(void* const* d_in, const int* in_sizes, int n_in,
                              void* d_out, int out_size, void* d_ws, size_t ws_size,
                              hipStream_t stream)
{
    const float* e     = (const float*)d_in[0];
    const float* d     = (const float*)d_in[1];
    const float* temp  = (const float*)d_in[2];
    const float* w_qkv = (const float*)d_in[3];
    const float* w_dw  = (const float*)d_in[4];
    const float* w_p1  = (const float*)d_in[5];
    const float* w_p2  = (const float*)d_in[6];
    const float* w_p3  = (const float*)d_in[7];
    const float* w_p4  = (const float*)d_in[8];
    float* out = (float*)d_out;
    float* ws  = (float*)d_ws;

    // workspace layout (float units)
    bf16_t* zraw = (bf16_t*)ws;                // 75,497,472 bf16 (qkv raw)
    bf16_t* zb   = (bf16_t*)(ws + 37748736L);  // 75,497,472 bf16
    float* attn  = ws + 75497472L;             // 147,456
    float* invn  = ws + 75644928L;             // 3,072
    // part & M reuse the zraw region once it's dead (after dwconv3b)
    float* part  = ws;                         // 4,718,592 f32
    float* Mmat  = ws + 8388608L;              // 589,824 f32

    const long sXin = (long)CC * N_PIX;
    const long sQKV = (long)C3 * N_PIX;

    // 1) pointwise qkv GEMM, bf16 output
    GArgs gq{};
    for (int bt = 0; bt < 16; ++bt) { gq.W[bt] = w_qkv; gq.xoff[bt] = (long)(bt & 3) * sXin; }
    gemm_k192<float, bf16_t><<<dim3(64, 9, 4), 256, 0, stream>>>(gq, e, zraw, sQKV);
    gemm_k192<float, bf16_t><<<dim3(64, 9, 4), 256, 0, stream>>>(gq, d, zraw + 4L * sQKV, sQKV);
    // 2) depthwise 3x3 (bf16 -> bf16) + fused q/k row norms
    dwconv3b<<<dim3(C3, 8), 256, 0, stream>>>(zraw, w_dw, zb, invn);
    // 3) MFMA score partials, 4 combos fused (part reuses dead zraw region)
    scores_mfma<<<dim3(NCH, 16), 256, 0, stream>>>(zb, part);
    // 4) reduce + scale + softmax
    reduce_softmax<<<dim3(64), 256, 0, stream>>>(part, invn, temp, attn);
    // 5) fold attn into projection matrices
    WPtrs wpj; wpj.p[0] = w_p1; wpj.p[1] = w_p2; wpj.p[2] = w_p3; wpj.p[3] = w_p4;
    make_M<<<dim3(64), 256, 0, stream>>>(attn, wpj, Mmat);
    // 6) fused (proj ∘ attn) @ V directly into d_out (V is bf16)
    GArgs gm{};
    for (int bt = 0; bt < 16; ++bt) {
        const int m = bt >> 2, b = bt & 3;
        const int ks = (m == 1 || m == 2) ? 1 : 0;
        gm.W[bt] = Mmat + (long)bt * 192 * 192;
        gm.xoff[bt] = ((long)((ks * 4 + b) * C3 + 384)) * N_PIX;
    }
    gemm_k192<bf16_t, float><<<dim3(64, 3, 16), 256, 0, stream>>>(gm, zb, out, sXin);
}

// Round 9
// 378.497 us; speedup vs baseline: 1.0429x; 1.0429x over previous
//
#include <hip/hip_runtime.h>

#define N_PIX 16384
#define CC 192
#define C3 576
#define KTOT 192
#define NCH 32
#define CHUNK 512

typedef __bf16 bf16_t;
typedef bf16_t bf16x4 __attribute__((ext_vector_type(4)));
typedef bf16_t bf16x8 __attribute__((ext_vector_type(8)));
typedef float f32x4 __attribute__((ext_vector_type(4)));

struct WPtrs { const float* p[4]; };
struct GArgs { const float* W[16]; long xoff[16]; int sel[16]; };

// ---------------- MFMA GEMM: Y[m][n] = sum_k W[m][k] * X[k][n], K=192 --------
// 64m x 256n tile. W staged to LDS once for all K. X single-buffer register
// prefetch (round-7 structure: ~150 VGPR -> 3 waves/SIMD; the xa/xb double
// buffer pushed ~210 VGPR -> 2 waves/SIMD and LOST 35us on this latency-bound
// kernel). A/B frags share k-bijection phi(gi,e)=16*(e>>2)+4*gi+(e&3);
// C/D map col=lane&15, row=4*(lane>>4)+reg [m89-verified].
template <typename XT, typename YT>
__global__ __launch_bounds__(256) void gemm_k192(GArgs ga,
    const XT* __restrict__ X0, const XT* __restrict__ X1,
    YT* __restrict__ Y, long sY)
{
    __shared__ __align__(16) bf16_t Wl[64][200];   // 64m x 192k (+8 pad)
    __shared__ __align__(16) bf16_t Xl[256][36];   // 256n x 32k (+4 pad)
    const int bt = blockIdx.z;
    const float* __restrict__ W = ga.W[bt];
    const XT* __restrict__ Xb = (ga.sel[bt] ? X1 : X0) + ga.xoff[bt];
    YT* __restrict__ Yb = Y + (long)bt * sY;
    const int m0 = blockIdx.y * 64, n0 = blockIdx.x * 256;
    const int tid = threadIdx.x;
    const int w = tid >> 6;
    const int gi = (tid >> 4) & 3;
    const int li = tid & 15;

    // stage all of W: 4 threads/row, each 48 k = 6 bf16x8 segments
    {
        const int wr = tid >> 2, wkb = (tid & 3) * 48;
        #pragma unroll
        for (int j = 0; j < 6; ++j) {
            const float* wp0 = W + (long)(m0 + wr) * KTOT + wkb + 8 * j;
            float4 a = *(const float4*)(wp0);
            float4 b = *(const float4*)(wp0 + 4);
            bf16x8 v = { (bf16_t)a.x, (bf16_t)a.y, (bf16_t)a.z, (bf16_t)a.w,
                         (bf16_t)b.x, (bf16_t)b.y, (bf16_t)b.z, (bf16_t)b.w };
            *(bf16x8*)&Wl[wr][wkb + 8 * j] = v;
        }
    }

    f32x4 acc[4][4];
    #pragma unroll
    for (int i = 0; i < 4; ++i)
        #pragma unroll
        for (int j = 0; j < 4; ++j) acc[i][j] = 0.f;

    XT xr[32];
    auto loadX = [&](int t) {
        const XT* xp = Xb + (long)(t * 32) * N_PIX + n0 + tid;
        #pragma unroll
        for (int g = 0; g < 32; ++g) xr[g] = xp[(long)g * N_PIX];
    };

    loadX(0);
    for (int t = 0; t < 6; ++t) {
        // write prefetched regs -> LDS (column tid)
        #pragma unroll
        for (int g = 0; g < 8; ++g) {
            bf16x4 v = { (bf16_t)xr[4 * g + 0], (bf16_t)xr[4 * g + 1],
                         (bf16_t)xr[4 * g + 2], (bf16_t)xr[4 * g + 3] };
            *(bf16x4*)&Xl[tid][g * 4] = v;
        }
        __syncthreads();
        if (t < 5) loadX(t + 1);    // issue next tile's loads under the MFMAs
        bf16x8 af[4], bfr[4];
        #pragma unroll
        for (int mi = 0; mi < 4; ++mi) {
            bf16x4 lo = *(const bf16x4*)&Wl[16 * mi + li][32 * t + 4 * gi];
            bf16x4 hi = *(const bf16x4*)&Wl[16 * mi + li][32 * t + 16 + 4 * gi];
            af[mi] = __builtin_shufflevector(lo, hi, 0, 1, 2, 3, 4, 5, 6, 7);
        }
        #pragma unroll
        for (int ni = 0; ni < 4; ++ni) {
            const int n = 64 * w + 16 * ni + li;
            bf16x4 lo = *(const bf16x4*)&Xl[n][4 * gi];
            bf16x4 hi = *(const bf16x4*)&Xl[n][16 + 4 * gi];
            bfr[ni] = __builtin_shufflevector(lo, hi, 0, 1, 2, 3, 4, 5, 6, 7);
        }
        #pragma unroll
        for (int mi = 0; mi < 4; ++mi)
            #pragma unroll
            for (int ni = 0; ni < 4; ++ni)
                acc[mi][ni] = __builtin_amdgcn_mfma_f32_16x16x32_bf16(
                    af[mi], bfr[ni], acc[mi][ni], 0, 0, 0);
        __syncthreads();
    }
    #pragma unroll
    for (int mi = 0; mi < 4; ++mi)
        #pragma unroll
        for (int ni = 0; ni < 4; ++ni) {
            const int n = n0 + 64 * w + 16 * ni + li;
            #pragma unroll
            for (int r = 0; r < 4; ++r) {
                const int m = m0 + 16 * mi + 4 * gi + r;
                Yb[(long)m * N_PIX + n] = (YT)acc[mi][ni][r];
            }
        }
}

// ---------------- depthwise 3x3 + fused row L2-norm ----------------
// One block = one (channel, image) = one full norm row. For ch<384 (q,k),
// block-reduce sum(z^2) over the 128x128 output and write invn directly.
__global__ __launch_bounds__(256) void dwconv3b(const bf16_t* __restrict__ Yin,
    const float* __restrict__ wdw, bf16_t* __restrict__ Z,
    float* __restrict__ invn)
{
    const int ch = blockIdx.x, sb = blockIdx.y;
    const int tid = threadIdx.x;
    const int x0 = (tid & 15) << 3;          // 16 col-groups x 8
    const int y0 = (tid >> 4) << 3;          // 16 row-strips x 8
    const bf16_t* __restrict__ inp = Yin + (long)(sb * C3 + ch) * N_PIX;
    bf16_t* __restrict__ outp = Z + (long)(sb * C3 + ch) * N_PIX;
    const float* wch = wdw + ch * 9;
    const float w00 = wch[0], w01 = wch[1], w02 = wch[2];
    const float w10 = wch[3], w11 = wch[4], w12 = wch[5];
    const float w20 = wch[6], w21 = wch[7], w22 = wch[8];
    const bool hasL = (x0 > 0), hasR = (x0 < 120);
    float A[10], B[10], Cr[10];   // [0]=x0-1, [1..8]=x0..x0+7, [9]=x0+8
    auto loadrow = [&](int yy, float* r) {
        if (yy < 0 || yy > 127) {
            #pragma unroll
            for (int i = 0; i < 10; ++i) r[i] = 0.f;
            return;
        }
        const bf16_t* p = inp + (yy << 7);
        bf16x8 v = *(const bf16x8*)(p + x0);
        #pragma unroll
        for (int j = 0; j < 8; ++j) r[1 + j] = (float)v[j];
        r[0] = hasL ? (float)p[x0 - 1] : 0.f;
        r[9] = hasR ? (float)p[x0 + 8] : 0.f;
    };
    loadrow(y0 - 1, A);
    loadrow(y0,     B);
    float ss = 0.f;
    #pragma unroll
    for (int r = 0; r < 8; ++r) {
        loadrow(y0 + r + 1, Cr);
        bf16x8 ov;
        #pragma unroll
        for (int i = 0; i < 8; ++i) {
            float s;
            s = fmaf(w00, A[i],  fmaf(w01, A[i + 1],  w02 * A[i + 2]));
            s = fmaf(w10, B[i],  fmaf(w11, B[i + 1],  fmaf(w12, B[i + 2], s)));
            s = fmaf(w20, Cr[i], fmaf(w21, Cr[i + 1], fmaf(w22, Cr[i + 2], s)));
            ov[i] = (bf16_t)s;
            const float vb = (float)ov[i];   // norm of the bf16-rounded value
            ss = fmaf(vb, vb, ss);
        }
        *(bf16x8*)(outp + ((y0 + r) << 7) + x0) = ov;
        #pragma unroll
        for (int i = 0; i < 10; ++i) { A[i] = B[i]; B[i] = Cr[i]; }
    }
    if (ch < 384) {
        #pragma unroll
        for (int off = 32; off > 0; off >>= 1) ss += __shfl_down(ss, off);
        __shared__ float red[4];
        if ((tid & 63) == 0) red[tid >> 6] = ss;
        __syncthreads();
        if (tid == 0) {
            const float t = red[0] + red[1] + red[2] + red[3];
            const int row = (sb >> 2) * 1536 + (sb & 3) * 384 + ch;
            invn[row] = 1.f / fmaxf(sqrtf(t), 1e-12f);
        }
    }
}

// ---------------- MFMA score partials: all 4 combos share one LDS stage ------
// block = (chunk, b*4+h); wave m = combo (ee, dd, ed, de).
__global__ __launch_bounds__(256) void scores_mfma(const bf16_t* __restrict__ Z,
                                                   float* __restrict__ part)
{
    const int c = blockIdx.x;
    const int bh = blockIdx.y;
    const int b = bh >> 2, h = bh & 3;
    __shared__ __align__(16) bf16_t T[4][48][72];   // qe, qd, ke, kd
    const int tid = threadIdx.x;
    const int m = tid >> 6;
    const int gi = (tid >> 4) & 3, li = tid & 15;
    const int qs = (m == 1 || m == 3) ? 1 : 0;
    const int ks = (m == 1 || m == 2) ? 1 : 0;
    f32x4 acc[3][3];
    #pragma unroll
    for (int i = 0; i < 3; ++i)
        #pragma unroll
        for (int j = 0; j < 3; ++j) acc[i][j] = 0.f;

    const int nbase = c * CHUNK;
    for (int k0 = 0; k0 < CHUNK; k0 += 64) {
        __syncthreads();
        for (int l = tid; l < 1536; l += 256) {
            const int t = l / 384;
            const int rem = l - t * 384;
            const int r = rem >> 3, s = rem & 7;
            const int sidx = (t < 2) ? t : (t - 2);
            const int qk = (t < 2) ? 0 : 1;
            const bf16_t* gp = Z + ((long)((sidx * 4 + b) * C3 + qk * 192 + h * 48 + r)) * N_PIX
                                 + nbase + k0 + s * 8;
            *(bf16x8*)&T[t][r][s * 8] = *(const bf16x8*)gp;
        }
        __syncthreads();
        #pragma unroll
        for (int k2 = 0; k2 < 64; k2 += 32) {
            bf16x8 af[3], bfr[3];
            #pragma unroll
            for (int i = 0; i < 3; ++i) {
                bf16x4 lo = *(const bf16x4*)&T[qs][16 * i + li][k2 + 4 * gi];
                bf16x4 hi = *(const bf16x4*)&T[qs][16 * i + li][k2 + 16 + 4 * gi];
                af[i] = __builtin_shufflevector(lo, hi, 0, 1, 2, 3, 4, 5, 6, 7);
            }
            #pragma unroll
            for (int j = 0; j < 3; ++j) {
                bf16x4 lo = *(const bf16x4*)&T[2 + ks][16 * j + li][k2 + 4 * gi];
                bf16x4 hi = *(const bf16x4*)&T[2 + ks][16 * j + li][k2 + 16 + 4 * gi];
                bfr[j] = __builtin_shufflevector(lo, hi, 0, 1, 2, 3, 4, 5, 6, 7);
            }
            #pragma unroll
            for (int i = 0; i < 3; ++i)
                #pragma unroll
                for (int j = 0; j < 3; ++j)
                    acc[i][j] = __builtin_amdgcn_mfma_f32_16x16x32_bf16(
                        af[i], bfr[j], acc[i][j], 0, 0, 0);
        }
    }
    const long base = ((long)(m * 16 + bh) * NCH + c) * 2304;
    #pragma unroll
    for (int i = 0; i < 3; ++i)
        #pragma unroll
        for (int j = 0; j < 3; ++j) {
            const int e = 16 * j + li;
            #pragma unroll
            for (int r = 0; r < 4; ++r) {
                const int d = 16 * i + 4 * gi + r;
                part[base + d * 48 + e] = acc[i][j][r];
            }
        }
}

// ---------------- reduce partials, scale by norms+temperature, softmax -------
__global__ __launch_bounds__(256) void reduce_softmax(const float* __restrict__ part,
    const float* __restrict__ invn, const float* __restrict__ temp,
    float* __restrict__ attn)
{
    const int mbh = blockIdx.x;                 // 64
    const int m = mbh >> 4, b = (mbh >> 2) & 3, h = mbh & 3;
    const int qs = (m == 1 || m == 3) ? 1 : 0;
    const int ks = (m == 1 || m == 2) ? 1 : 0;
    __shared__ float sm[48][48];
    const int tid = threadIdx.x;
    const long pbase = (long)mbh * NCH * 2304;
    const float T = temp[h];
    for (int idx = tid; idx < 2304; idx += 256) {
        float v = 0.f;
        #pragma unroll 8
        for (int c = 0; c < NCH; ++c) v += part[pbase + c * 2304 + idx];
        const int d = idx / 48, e = idx % 48;
        const float iq = invn[(qs * 4 + b) * 384 + h * 48 + d];
        const float ik = invn[(ks * 4 + b) * 384 + 192 + h * 48 + e];
        sm[d][e] = v * iq * ik * T;
    }
    __syncthreads();
    if (tid < 48) {
        float mx = -1e30f;
        #pragma unroll
        for (int e = 0; e < 48; ++e) mx = fmaxf(mx, sm[tid][e]);
        float sum = 0.f;
        #pragma unroll
        for (int e = 0; e < 48; ++e) {
            const float v = __expf(sm[tid][e] - mx);
            sm[tid][e] = v;
            sum += v;
        }
        const float inv = 1.f / sum;
        const long abase = (long)mbh * 2304 + (long)tid * 48;
        #pragma unroll
        for (int e = 0; e < 48; ++e) attn[abase + e] = sm[tid][e] * inv;
    }
}

// ---------------- fold attn into projection: M[m][b][o][h*48+e] --------------
// m==3 (inter_de): einsum '...de,bhen->bhdn' SUMS the ellipsis dims.
__global__ __launch_bounds__(256) void make_M(const float* __restrict__ attn,
                                              WPtrs wp, float* __restrict__ M)
{
    const int h = blockIdx.x & 3;
    const int b = (blockIdx.x >> 2) & 3;
    const int m = blockIdx.x >> 4;              // grid 64
    __shared__ float A[48][48];
    const int tid = threadIdx.x;
    if (m == 3) {
        for (int l = tid; l < 2304; l += 256) {
            float s = 0.f;
            #pragma unroll
            for (int bb = 0; bb < 16; ++bb)
                s += attn[(long)(48 + bb) * 2304 + l];
            A[l / 48][l % 48] = s;
        }
    } else {
        const long ab = (long)(m * 16 + b * 4 + h) * 2304;
        for (int l = tid; l < 2304; l += 256)
            A[l / 48][l % 48] = attn[ab + l];
    }
    __syncthreads();
    const float* W = wp.p[m];
    float* Mo = M + (long)(m * 4 + b) * 192 * 192;
    for (int o = tid >> 4; o < 192; o += 16) {
        const float* wrow = W + (long)o * 192 + h * 48;
        for (int e2 = tid & 15; e2 < 48; e2 += 16) {
            float s = 0.f;
            #pragma unroll
            for (int d = 0; d < 48; ++d) s = fmaf(wrow[d], A[d][e2], s);
            Mo[(long)o * 192 + h * 48 + e2] = s;
        }
    }
}

extern "C" void kernel_launch(void* const* d_in, const int* in_sizes, int n_in,
                              void* d_out, int out_size, void* d_ws, size_t ws_size,
                              hipStream_t stream)
{
    const float* e     = (const float*)d_in[0];
    const float* d     = (const float*)d_in[1];
    const float* temp  = (const float*)d_in[2];
    const float* w_qkv = (const float*)d_in[3];
    const float* w_dw  = (const float*)d_in[4];
    const float* w_p1  = (const float*)d_in[5];
    const float* w_p2  = (const float*)d_in[6];
    const float* w_p3  = (const float*)d_in[7];
    const float* w_p4  = (const float*)d_in[8];
    float* out = (float*)d_out;
    float* ws  = (float*)d_ws;

    // workspace layout (float units)
    bf16_t* zraw = (bf16_t*)ws;                // 75,497,472 bf16 (qkv raw)
    bf16_t* zb   = (bf16_t*)(ws + 37748736L);  // 75,497,472 bf16
    float* attn  = ws + 75497472L;             // 147,456
    float* invn  = ws + 75644928L;             // 3,072
    // part & M reuse the zraw region once it's dead (after dwconv3b)
    float* part  = ws;                         // 4,718,592 f32
    float* Mmat  = ws + 8388608L;              // 589,824 f32

    const long sXin = (long)CC * N_PIX;
    const long sQKV = (long)C3 * N_PIX;

    // 1) pointwise qkv GEMM, bf16 output — ONE launch for e (bt 0..3, X0) and
    //    d (bt 4..7, X1): d-GEMM ramp overlaps e-GEMM drain.
    GArgs gq{};
    for (int bt = 0; bt < 8; ++bt) {
        gq.W[bt] = w_qkv;
        gq.xoff[bt] = (long)(bt & 3) * sXin;
        gq.sel[bt] = bt >> 2;
    }
    gemm_k192<float, bf16_t><<<dim3(64, 9, 8), 256, 0, stream>>>(gq, e, d, zraw, sQKV);
    // 2) depthwise 3x3 (bf16 -> bf16) + fused q/k row norms
    dwconv3b<<<dim3(C3, 8), 256, 0, stream>>>(zraw, w_dw, zb, invn);
    // 3) MFMA score partials, 4 combos fused (part reuses dead zraw region)
    scores_mfma<<<dim3(NCH, 16), 256, 0, stream>>>(zb, part);
    // 4) reduce + scale + softmax
    reduce_softmax<<<dim3(64), 256, 0, stream>>>(part, invn, temp, attn);
    // 5) fold attn into projection matrices
    WPtrs wpj; wpj.p[0] = w_p1; wpj.p[1] = w_p2; wpj.p[2] = w_p3; wpj.p[3] = w_p4;
    make_M<<<dim3(64), 256, 0, stream>>>(attn, wpj, Mmat);
    // 6) fused (proj ∘ attn) @ V directly into d_out (V is bf16)
    GArgs gm{};
    for (int bt = 0; bt < 16; ++bt) {
        const int m = bt >> 2, b = bt & 3;
        const int ks = (m == 1 || m == 2) ? 1 : 0;
        gm.W[bt] = Mmat + (long)bt * 192 * 192;
        gm.xoff[bt] = ((long)((ks * 4 + b) * C3 + 384)) * N_PIX;
        gm.sel[bt] = 0;
    }
    gemm_k192<bf16_t, float><<<dim3(64, 3, 16), 256, 0, stream>>>(gm, zb, zb, out, sXin);
}

// Round 10
// 371.664 us; speedup vs baseline: 1.0620x; 1.0184x over previous
//
#include <hip/hip_runtime.h>

#define N_PIX 16384
#define CC 192
#define C3 576
#define KTOT 192
#define NCH 32
#define CHUNK 512

typedef __bf16 bf16_t;
typedef bf16_t bf16x4 __attribute__((ext_vector_type(4)));
typedef bf16_t bf16x8 __attribute__((ext_vector_type(8)));
typedef float f32x4 __attribute__((ext_vector_type(4)));

struct WPtrs { const float* p[4]; };
struct GArgs { const float* W[16]; long xoff[16]; int sel[16]; };

// ---------------- MFMA GEMM: Y[m][n] = sum_k W[m][k] * X[k][n], K=192 --------
// 64m x 256n tile, K-step 32. LDS cut to 22.5KB (per-k-tile W staging instead
// of full-K: 44KB was capping occupancy at 3 blocks/CU; this kernel is pure
// latency-bound so blocks/CU is THE lever). X and W both reg-prefetched with
// loads issued BEFORE the first barrier (window spans both barriers + frags +
// MFMAs). A/B frags share k-bijection phi(gi,e)=16*(e>>2)+4*gi+(e&3);
// C/D map col=lane&15, row=4*(lane>>4)+reg [m89-verified].
template <typename XT, typename YT>
__global__ __launch_bounds__(256) void gemm_k192(GArgs ga,
    const XT* __restrict__ X0, const XT* __restrict__ X1,
    YT* __restrict__ Y, long sY)
{
    __shared__ __align__(16) bf16_t Wl[64][36];    // 64 m x 32 k (+pad)  4.5KB
    __shared__ __align__(16) bf16_t Xl[256][36];   // 256 n x 32 k (+pad) 18KB
    const int bt = blockIdx.z;
    const float* __restrict__ W = ga.W[bt];
    const XT* __restrict__ Xb = (ga.sel[bt] ? X1 : X0) + ga.xoff[bt];
    YT* __restrict__ Yb = Y + (long)bt * sY;
    const int m0 = blockIdx.y * 64, n0 = blockIdx.x * 256;
    const int tid = threadIdx.x;
    const int w = tid >> 6;
    const int gi = (tid >> 4) & 3;
    const int li = tid & 15;
    const int wr = tid >> 2, wk = (tid & 3) << 3;   // W staging coords

    f32x4 acc[4][4];
    #pragma unroll
    for (int i = 0; i < 4; ++i)
        #pragma unroll
        for (int j = 0; j < 4; ++j) acc[i][j] = 0.f;

    XT xr[32];
    float wreg[8];
    auto loadX = [&](int t) {
        const XT* xp = Xb + (long)(t * 32) * N_PIX + n0 + tid;
        #pragma unroll
        for (int g = 0; g < 32; ++g) xr[g] = xp[(long)g * N_PIX];
    };
    auto loadW = [&](int t) {
        const float* wp0 = W + (long)(m0 + wr) * KTOT + t * 32 + wk;
        float4 a = *(const float4*)(wp0);
        float4 b = *(const float4*)(wp0 + 4);
        wreg[0] = a.x; wreg[1] = a.y; wreg[2] = a.z; wreg[3] = a.w;
        wreg[4] = b.x; wreg[5] = b.y; wreg[6] = b.z; wreg[7] = b.w;
    };

    loadX(0); loadW(0);
    for (int t = 0; t < 6; ++t) {
        // write prefetched regs -> LDS
        #pragma unroll
        for (int g = 0; g < 8; ++g) {
            bf16x4 v = { (bf16_t)xr[4 * g + 0], (bf16_t)xr[4 * g + 1],
                         (bf16_t)xr[4 * g + 2], (bf16_t)xr[4 * g + 3] };
            *(bf16x4*)&Xl[tid][g * 4] = v;
        }
        {
            bf16x4 lo = { (bf16_t)wreg[0], (bf16_t)wreg[1], (bf16_t)wreg[2], (bf16_t)wreg[3] };
            bf16x4 hi = { (bf16_t)wreg[4], (bf16_t)wreg[5], (bf16_t)wreg[6], (bf16_t)wreg[7] };
            *(bf16x4*)&Wl[wr][wk]     = lo;     // 8B stores: 72B row stride is
            *(bf16x4*)&Wl[wr][wk + 4] = hi;     // 8B- but not 16B-aligned
        }
        // issue next tile's loads BEFORE the barrier: latency window spans
        // barrier + frag ds_reads + 16 MFMAs + barrier + next LDS write
        if (t < 5) { loadX(t + 1); loadW(t + 1); }
        __syncthreads();
        bf16x8 af[4], bfr[4];
        #pragma unroll
        for (int mi = 0; mi < 4; ++mi) {
            bf16x4 lo = *(const bf16x4*)&Wl[16 * mi + li][4 * gi];
            bf16x4 hi = *(const bf16x4*)&Wl[16 * mi + li][16 + 4 * gi];
            af[mi] = __builtin_shufflevector(lo, hi, 0, 1, 2, 3, 4, 5, 6, 7);
        }
        #pragma unroll
        for (int ni = 0; ni < 4; ++ni) {
            const int n = 64 * w + 16 * ni + li;
            bf16x4 lo = *(const bf16x4*)&Xl[n][4 * gi];
            bf16x4 hi = *(const bf16x4*)&Xl[n][16 + 4 * gi];
            bfr[ni] = __builtin_shufflevector(lo, hi, 0, 1, 2, 3, 4, 5, 6, 7);
        }
        #pragma unroll
        for (int mi = 0; mi < 4; ++mi)
            #pragma unroll
            for (int ni = 0; ni < 4; ++ni)
                acc[mi][ni] = __builtin_amdgcn_mfma_f32_16x16x32_bf16(
                    af[mi], bfr[ni], acc[mi][ni], 0, 0, 0);
        __syncthreads();
    }
    #pragma unroll
    for (int mi = 0; mi < 4; ++mi)
        #pragma unroll
        for (int ni = 0; ni < 4; ++ni) {
            const int n = n0 + 64 * w + 16 * ni + li;
            #pragma unroll
            for (int r = 0; r < 4; ++r) {
                const int m = m0 + 16 * mi + 4 * gi + r;
                Yb[(long)m * N_PIX + n] = (YT)acc[mi][ni][r];
            }
        }
}

// ---------------- depthwise 3x3 + fused row L2-norm ----------------
// One block = one (channel, image) = one full norm row. For ch<384 (q,k),
// block-reduce sum(z^2) over the 128x128 output and write invn directly.
__global__ __launch_bounds__(256) void dwconv3b(const bf16_t* __restrict__ Yin,
    const float* __restrict__ wdw, bf16_t* __restrict__ Z,
    float* __restrict__ invn)
{
    const int ch = blockIdx.x, sb = blockIdx.y;
    const int tid = threadIdx.x;
    const int x0 = (tid & 15) << 3;          // 16 col-groups x 8
    const int y0 = (tid >> 4) << 3;          // 16 row-strips x 8
    const bf16_t* __restrict__ inp = Yin + (long)(sb * C3 + ch) * N_PIX;
    bf16_t* __restrict__ outp = Z + (long)(sb * C3 + ch) * N_PIX;
    const float* wch = wdw + ch * 9;
    const float w00 = wch[0], w01 = wch[1], w02 = wch[2];
    const float w10 = wch[3], w11 = wch[4], w12 = wch[5];
    const float w20 = wch[6], w21 = wch[7], w22 = wch[8];
    const bool hasL = (x0 > 0), hasR = (x0 < 120);
    float A[10], B[10], Cr[10];   // [0]=x0-1, [1..8]=x0..x0+7, [9]=x0+8
    auto loadrow = [&](int yy, float* r) {
        if (yy < 0 || yy > 127) {
            #pragma unroll
            for (int i = 0; i < 10; ++i) r[i] = 0.f;
            return;
        }
        const bf16_t* p = inp + (yy << 7);
        bf16x8 v = *(const bf16x8*)(p + x0);
        #pragma unroll
        for (int j = 0; j < 8; ++j) r[1 + j] = (float)v[j];
        r[0] = hasL ? (float)p[x0 - 1] : 0.f;
        r[9] = hasR ? (float)p[x0 + 8] : 0.f;
    };
    loadrow(y0 - 1, A);
    loadrow(y0,     B);
    float ss = 0.f;
    #pragma unroll
    for (int r = 0; r < 8; ++r) {
        loadrow(y0 + r + 1, Cr);
        bf16x8 ov;
        #pragma unroll
        for (int i = 0; i < 8; ++i) {
            float s;
            s = fmaf(w00, A[i],  fmaf(w01, A[i + 1],  w02 * A[i + 2]));
            s = fmaf(w10, B[i],  fmaf(w11, B[i + 1],  fmaf(w12, B[i + 2], s)));
            s = fmaf(w20, Cr[i], fmaf(w21, Cr[i + 1], fmaf(w22, Cr[i + 2], s)));
            ov[i] = (bf16_t)s;
            const float vb = (float)ov[i];   // norm of the bf16-rounded value
            ss = fmaf(vb, vb, ss);
        }
        *(bf16x8*)(outp + ((y0 + r) << 7) + x0) = ov;
        #pragma unroll
        for (int i = 0; i < 10; ++i) { A[i] = B[i]; B[i] = Cr[i]; }
    }
    if (ch < 384) {
        #pragma unroll
        for (int off = 32; off > 0; off >>= 1) ss += __shfl_down(ss, off);
        __shared__ float red[4];
        if ((tid & 63) == 0) red[tid >> 6] = ss;
        __syncthreads();
        if (tid == 0) {
            const float t = red[0] + red[1] + red[2] + red[3];
            const int row = (sb >> 2) * 1536 + (sb & 3) * 384 + ch;
            invn[row] = 1.f / fmaxf(sqrtf(t), 1e-12f);
        }
    }
}

// ---------------- MFMA score partials: all 4 combos share one LDS stage ------
// block = (chunk, b*4+h); wave m = combo (ee, dd, ed, de).
__global__ __launch_bounds__(256) void scores_mfma(const bf16_t* __restrict__ Z,
                                                   float* __restrict__ part)
{
    const int c = blockIdx.x;
    const int bh = blockIdx.y;
    const int b = bh >> 2, h = bh & 3;
    __shared__ __align__(16) bf16_t T[4][48][72];   // qe, qd, ke, kd
    const int tid = threadIdx.x;
    const int m = tid >> 6;
    const int gi = (tid >> 4) & 3, li = tid & 15;
    const int qs = (m == 1 || m == 3) ? 1 : 0;
    const int ks = (m == 1 || m == 2) ? 1 : 0;
    f32x4 acc[3][3];
    #pragma unroll
    for (int i = 0; i < 3; ++i)
        #pragma unroll
        for (int j = 0; j < 3; ++j) acc[i][j] = 0.f;

    const int nbase = c * CHUNK;
    for (int k0 = 0; k0 < CHUNK; k0 += 64) {
        __syncthreads();
        for (int l = tid; l < 1536; l += 256) {
            const int t = l / 384;
            const int rem = l - t * 384;
            const int r = rem >> 3, s = rem & 7;
            const int sidx = (t < 2) ? t : (t - 2);
            const int qk = (t < 2) ? 0 : 1;
            const bf16_t* gp = Z + ((long)((sidx * 4 + b) * C3 + qk * 192 + h * 48 + r)) * N_PIX
                                 + nbase + k0 + s * 8;
            *(bf16x8*)&T[t][r][s * 8] = *(const bf16x8*)gp;
        }
        __syncthreads();
        #pragma unroll
        for (int k2 = 0; k2 < 64; k2 += 32) {
            bf16x8 af[3], bfr[3];
            #pragma unroll
            for (int i = 0; i < 3; ++i) {
                bf16x4 lo = *(const bf16x4*)&T[qs][16 * i + li][k2 + 4 * gi];
                bf16x4 hi = *(const bf16x4*)&T[qs][16 * i + li][k2 + 16 + 4 * gi];
                af[i] = __builtin_shufflevector(lo, hi, 0, 1, 2, 3, 4, 5, 6, 7);
            }
            #pragma unroll
            for (int j = 0; j < 3; ++j) {
                bf16x4 lo = *(const bf16x4*)&T[2 + ks][16 * j + li][k2 + 4 * gi];
                bf16x4 hi = *(const bf16x4*)&T[2 + ks][16 * j + li][k2 + 16 + 4 * gi];
                bfr[j] = __builtin_shufflevector(lo, hi, 0, 1, 2, 3, 4, 5, 6, 7);
            }
            #pragma unroll
            for (int i = 0; i < 3; ++i)
                #pragma unroll
                for (int j = 0; j < 3; ++j)
                    acc[i][j] = __builtin_amdgcn_mfma_f32_16x16x32_bf16(
                        af[i], bfr[j], acc[i][j], 0, 0, 0);
        }
    }
    const long base = ((long)(m * 16 + bh) * NCH + c) * 2304;
    #pragma unroll
    for (int i = 0; i < 3; ++i)
        #pragma unroll
        for (int j = 0; j < 3; ++j) {
            const int e = 16 * j + li;
            #pragma unroll
            for (int r = 0; r < 4; ++r) {
                const int d = 16 * i + 4 * gi + r;
                part[base + d * 48 + e] = acc[i][j][r];
            }
        }
}

// ---------------- reduce partials, scale by norms+temperature, softmax -------
__global__ __launch_bounds__(256) void reduce_softmax(const float* __restrict__ part,
    const float* __restrict__ invn, const float* __restrict__ temp,
    float* __restrict__ attn)
{
    const int mbh = blockIdx.x;                 // 64
    const int m = mbh >> 4, b = (mbh >> 2) & 3, h = mbh & 3;
    const int qs = (m == 1 || m == 3) ? 1 : 0;
    const int ks = (m == 1 || m == 2) ? 1 : 0;
    __shared__ float sm[48][48];
    const int tid = threadIdx.x;
    const long pbase = (long)mbh * NCH * 2304;
    const float T = temp[h];
    for (int idx = tid; idx < 2304; idx += 256) {
        float v = 0.f;
        #pragma unroll 8
        for (int c = 0; c < NCH; ++c) v += part[pbase + c * 2304 + idx];
        const int d = idx / 48, e = idx % 48;
        const float iq = invn[(qs * 4 + b) * 384 + h * 48 + d];
        const float ik = invn[(ks * 4 + b) * 384 + 192 + h * 48 + e];
        sm[d][e] = v * iq * ik * T;
    }
    __syncthreads();
    if (tid < 48) {
        float mx = -1e30f;
        #pragma unroll
        for (int e = 0; e < 48; ++e) mx = fmaxf(mx, sm[tid][e]);
        float sum = 0.f;
        #pragma unroll
        for (int e = 0; e < 48; ++e) {
            const float v = __expf(sm[tid][e] - mx);
            sm[tid][e] = v;
            sum += v;
        }
        const float inv = 1.f / sum;
        const long abase = (long)mbh * 2304 + (long)tid * 48;
        #pragma unroll
        for (int e = 0; e < 48; ++e) attn[abase + e] = sm[tid][e] * inv;
    }
}

// ---------------- fold attn into projection: M[m][b][o][h*48+e] --------------
// m==3 (inter_de): einsum '...de,bhen->bhdn' SUMS the ellipsis dims.
__global__ __launch_bounds__(256) void make_M(const float* __restrict__ attn,
                                              WPtrs wp, float* __restrict__ M)
{
    const int h = blockIdx.x & 3;
    const int b = (blockIdx.x >> 2) & 3;
    const int m = blockIdx.x >> 4;              // grid 64
    __shared__ float A[48][48];
    const int tid = threadIdx.x;
    if (m == 3) {
        for (int l = tid; l < 2304; l += 256) {
            float s = 0.f;
            #pragma unroll
            for (int bb = 0; bb < 16; ++bb)
                s += attn[(long)(48 + bb) * 2304 + l];
            A[l / 48][l % 48] = s;
        }
    } else {
        const long ab = (long)(m * 16 + b * 4 + h) * 2304;
        for (int l = tid; l < 2304; l += 256)
            A[l / 48][l % 48] = attn[ab + l];
    }
    __syncthreads();
    const float* W = wp.p[m];
    float* Mo = M + (long)(m * 4 + b) * 192 * 192;
    for (int o = tid >> 4; o < 192; o += 16) {
        const float* wrow = W + (long)o * 192 + h * 48;
        for (int e2 = tid & 15; e2 < 48; e2 += 16) {
            float s = 0.f;
            #pragma unroll
            for (int d = 0; d < 48; ++d) s = fmaf(wrow[d], A[d][e2], s);
            Mo[(long)o * 192 + h * 48 + e2] = s;
        }
    }
}

extern "C" void kernel_launch(void* const* d_in, const int* in_sizes, int n_in,
                              void* d_out, int out_size, void* d_ws, size_t ws_size,
                              hipStream_t stream)
{
    const float* e     = (const float*)d_in[0];
    const float* d     = (const float*)d_in[1];
    const float* temp  = (const float*)d_in[2];
    const float* w_qkv = (const float*)d_in[3];
    const float* w_dw  = (const float*)d_in[4];
    const float* w_p1  = (const float*)d_in[5];
    const float* w_p2  = (const float*)d_in[6];
    const float* w_p3  = (const float*)d_in[7];
    const float* w_p4  = (const float*)d_in[8];
    float* out = (float*)d_out;
    float* ws  = (float*)d_ws;

    // workspace layout (float units)
    bf16_t* zraw = (bf16_t*)ws;                // 75,497,472 bf16 (qkv raw)
    bf16_t* zb   = (bf16_t*)(ws + 37748736L);  // 75,497,472 bf16
    float* attn  = ws + 75497472L;             // 147,456
    float* invn  = ws + 75644928L;             // 3,072
    // part & M reuse the zraw region once it's dead (after dwconv3b)
    float* part  = ws;                         // 4,718,592 f32
    float* Mmat  = ws + 8388608L;              // 589,824 f32

    const long sXin = (long)CC * N_PIX;
    const long sQKV = (long)C3 * N_PIX;

    // 1) pointwise qkv GEMM, bf16 output — ONE launch for e (bt 0..3, X0) and
    //    d (bt 4..7, X1): d-GEMM ramp overlaps e-GEMM drain.
    GArgs gq{};
    for (int bt = 0; bt < 8; ++bt) {
        gq.W[bt] = w_qkv;
        gq.xoff[bt] = (long)(bt & 3) * sXin;
        gq.sel[bt] = bt >> 2;
    }
    gemm_k192<float, bf16_t><<<dim3(64, 9, 8), 256, 0, stream>>>(gq, e, d, zraw, sQKV);
    // 2) depthwise 3x3 (bf16 -> bf16) + fused q/k row norms
    dwconv3b<<<dim3(C3, 8), 256, 0, stream>>>(zraw, w_dw, zb, invn);
    // 3) MFMA score partials, 4 combos fused (part reuses dead zraw region)
    scores_mfma<<<dim3(NCH, 16), 256, 0, stream>>>(zb, part);
    // 4) reduce + scale + softmax
    reduce_softmax<<<dim3(64), 256, 0, stream>>>(part, invn, temp, attn);
    // 5) fold attn into projection matrices
    WPtrs wpj; wpj.p[0] = w_p1; wpj.p[1] = w_p2; wpj.p[2] = w_p3; wpj.p[3] = w_p4;
    make_M<<<dim3(64), 256, 0, stream>>>(attn, wpj, Mmat);
    // 6) fused (proj ∘ attn) @ V directly into d_out (V is bf16)
    GArgs gm{};
    for (int bt = 0; bt < 16; ++bt) {
        const int m = bt >> 2, b = bt & 3;
        const int ks = (m == 1 || m == 2) ? 1 : 0;
        gm.W[bt] = Mmat + (long)bt * 192 * 192;
        gm.xoff[bt] = ((long)((ks * 4 + b) * C3 + 384)) * N_PIX;
        gm.sel[bt] = 0;
    }
    gemm_k192<bf16_t, float><<<dim3(64, 3, 16), 256, 0, stream>>>(gm, zb, zb, out, sXin);
}